// Round 4
// baseline (1808.518 us; speedup 1.0000x reference)
//
#include <hip/hip_runtime.h>

// LSTM(T=2048,B=256,IN=128,H=64) + FC(64).
//  prep:    split W_ih into bf16 hi/lo, bias = b_ih + b_hh
//  phase1:  xg = x@W_ih^T + bias (bf16 MFMA, 3-term split), stored PERMUTED
//           so phase2 lanes read their MFMA C-init as one 32B chunk.
//  lstm_fc: 16 blocks x 4 waves; each block owns 16 batch chains.
//           Per step: gates[16x256] = h[16x64] @ W_hh^T via 8x
//           mfma_f32_16x16x32_f16 per wave (wave w owns N-tiles
//           {w,4+w,8+w,12+w} => each lane holds i,f,g,o for its 4 (b,h)
//           pairs in-register). h exchanged through a 2KB xor-swizzled
//           f16 LDS double buffer; ONE raw s_barrier+lgkmcnt(0) per step
//           (no __syncthreads -> no vmcnt(0) drain, so the depth-4 xg
//           prefetch stays in flight). FC head fused: 2 MFMA on the
//           CURRENT step's A-frags (h_{t-1}), written to row t-1.
//  NOTE: the K-half-1 LDS read offset is rd_off ^ 64, NOT rd_off + 64 —
//  the XOR swizzle occupies bits 4-6, and +64 after the XOR carries into
//  bit 7 (row index) for col&4 lanes. (This was the round-1/2 bug.)

#define T_STEPS 2048
#define BATCH   256
#define INSZ    128
#define HID     64
#define G4      256   // 4*HID

typedef __attribute__((ext_vector_type(8))) short bf16x8;
typedef __attribute__((ext_vector_type(4))) float f32x4;
typedef __attribute__((ext_vector_type(8))) _Float16 f16x8;
typedef f16x8 __attribute__((may_alias)) f16x8_a;
typedef __attribute__((ext_vector_type(4))) short s16x4;

__device__ __forceinline__ short f2bf(float f) {
  unsigned u = __float_as_uint(f);
  unsigned r = (u + 0x7fffu + ((u >> 16) & 1u)) >> 16;
  return (short)r;
}
__device__ __forceinline__ float bf2f(short s) {
  return __uint_as_float(((unsigned)(unsigned short)s) << 16);
}
__device__ __forceinline__ float bflo(unsigned u) {
  return __uint_as_float(u << 16);
}
__device__ __forceinline__ float bfhi(unsigned u) {
  return __uint_as_float(u & 0xffff0000u);
}

#define LOG2E 1.44269504088896f
__device__ __forceinline__ float fast_sigmoid(float x) {
  float e = __builtin_amdgcn_exp2f(-LOG2E * x);
  return __builtin_amdgcn_rcpf(1.f + e);
}
__device__ __forceinline__ float fast_tanh(float x) {
  float e = __builtin_amdgcn_exp2f(-2.f * LOG2E * x);
  return fmaf(2.f, __builtin_amdgcn_rcpf(1.f + e), -1.f);
}

__device__ __forceinline__ f32x4 mfma16(bf16x8 a, bf16x8 b, f32x4 c) {
  return __builtin_amdgcn_mfma_f32_16x16x32_bf16(a, b, c, 0, 0, 0);
}
__device__ __forceinline__ f32x4 mfma_f16(f16x8 a, f16x8 b, f32x4 c) {
  return __builtin_amdgcn_mfma_f32_16x16x32_f16(a, b, c, 0, 0, 0);
}

// ---------------- prep: W_ih bf16 hi/lo split + bias sum ----------------
__global__ void prep_kernel(const float* __restrict__ W_ih,
                            const float* __restrict__ b_ih,
                            const float* __restrict__ b_hh,
                            short* __restrict__ Whi, short* __restrict__ Wlo,
                            float* __restrict__ bias) {
  int i = blockIdx.x * 256 + threadIdx.x;  // 128 blocks cover 32768
  float w = W_ih[i];
  short h = f2bf(w);
  Whi[i] = h;
  Wlo[i] = f2bf(w - bf2f(h));
  if (i < G4) bias[i] = b_ih[i] + b_hh[i];
}

// ---------------- phase 1: xg = x @ W_ih^T + bias (MFMA) ----------------
// Output layout (bf16 elems):
//   xg[ ((t*16 + Bk)*4 + w)*64*16 + lane*16 + tt*4 + r ]
//     = gates for batch b = Bk*16 + (lane>>4)*4 + r,
//       gate col g = tt*64 + 16*w + (lane&15)
// i.e. exactly the per-lane 16-value C-init chunk phase2 needs.
__global__ __launch_bounds__(256, 2) void phase1_kernel(
    const float* __restrict__ x, const short* __restrict__ Whi,
    const short* __restrict__ Wlo, const float* __restrict__ bias,
    short* __restrict__ xg) {
  int wave = threadIdx.x >> 6, lane = threadIdx.x & 63;
  int col = lane & 15, quad = lane >> 4;
  long rowbase = (long)blockIdx.x * 128 + wave * 32;

  bf16x8 Ah[2][4], Al[2][4];
#pragma unroll
  for (int rt = 0; rt < 2; ++rt) {
    const float* xp = x + (rowbase + rt * 16 + col) * INSZ + quad * 8;
#pragma unroll
    for (int kk = 0; kk < 4; ++kk) {
      float4 v0 = *(const float4*)(xp + kk * 32);
      float4 v1 = *(const float4*)(xp + kk * 32 + 4);
      bf16x8 hh, ll;
      float vv[8] = {v0.x, v0.y, v0.z, v0.w, v1.x, v1.y, v1.z, v1.w};
#pragma unroll
      for (int j = 0; j < 8; ++j) {
        short hb = f2bf(vv[j]);
        hh[j] = hb;
        ll[j] = f2bf(vv[j] - bf2f(hb));
      }
      Ah[rt][kk] = hh;
      Al[rt][kk] = ll;
    }
  }

  const long t = rowbase >> 8;                    // uniform per wave
  const int Bk0 = (int)((rowbase & 255) >> 4);    // even, rt adds +1

#pragma unroll 1
  for (int idx = 0; idx < 16; ++idx) {
    int w4 = idx >> 2, tt = idx & 3;              // w-major order
    int grow = (tt * 4 + w4) * 16 + col;
    const short* bph = Whi + grow * INSZ + quad * 8;
    const short* bpl = Wlo + grow * INSZ + quad * 8;
    f32x4 acc0 = {0.f, 0.f, 0.f, 0.f}, acc1 = {0.f, 0.f, 0.f, 0.f};
#pragma unroll
    for (int kk = 0; kk < 4; ++kk) {
      bf16x8 bh = *(const bf16x8*)(bph + kk * 32);
      bf16x8 bl = *(const bf16x8*)(bpl + kk * 32);
      acc0 = mfma16(Ah[0][kk], bh, acc0);
      acc1 = mfma16(Ah[1][kk], bh, acc1);
      acc0 = mfma16(Al[0][kk], bh, acc0);
      acc1 = mfma16(Al[1][kk], bh, acc1);
      acc0 = mfma16(Ah[0][kk], bl, acc0);
      acc1 = mfma16(Ah[1][kk], bl, acc1);
    }
    float bv = bias[grow];
    s16x4 v0, v1;
#pragma unroll
    for (int r = 0; r < 4; ++r) {
      v0[r] = f2bf(acc0[r] + bv);
      v1[r] = f2bf(acc1[r] + bv);
    }
    size_t e0 =
        ((((size_t)t * 16 + Bk0) * 4 + (size_t)w4) * 64 + lane) * 16 + tt * 4;
    *(s16x4*)(xg + e0) = v0;               // rt=0  (8B coalescible chunks)
    *(s16x4*)(xg + e0 + 4096) = v1;        // rt=1 -> Bk0+1
  }
}

// ---------------- phase 2: LSTM recurrence + fused FC, MFMA form ----------
// 16 blocks x 256 threads. Block = 16 batch chains. Wave w owns gate
// N-tiles {w,4+w,8+w,12+w} and FC N-tile w.
__global__ __launch_bounds__(256, 1) void lstm_fc_kernel(
    const short* __restrict__ xg, const float* __restrict__ W_hh,
    const float* __restrict__ W_fc, const float* __restrict__ b_fc,
    float* __restrict__ out) {
  const int tid = threadIdx.x;
  const int L = tid & 63, w = tid >> 6;
  const int col = L & 15, quad = L >> 4;
  const int Bk = blockIdx.x;

  __shared__ alignas(16) char hmem[2][2048];  // f16 h[16 b][64 k], swizzled

  // B-fragments: W_hh (4 gate tiles x 2 K-halves) + W_fc (2 K-halves), f16
  f16x8 whhB[4][2];
#pragma unroll
  for (int tt = 0; tt < 4; ++tt) {
    const float* wr = W_hh + (tt * 64 + 16 * w + col) * HID + quad * 8;
#pragma unroll
    for (int kh = 0; kh < 2; ++kh) {
      f16x8 f;
#pragma unroll
      for (int j = 0; j < 8; ++j) f[j] = (_Float16)wr[kh * 32 + j];
      whhB[tt][kh] = f;
    }
  }
  f16x8 wfcB[2];
  {
    const float* fr = W_fc + (16 * w + col) * HID + quad * 8;
#pragma unroll
    for (int kh = 0; kh < 2; ++kh) {
      f16x8 f;
#pragma unroll
      for (int j = 0; j < 8; ++j) f[j] = (_Float16)fr[kh * 32 + j];
      wfcB[kh] = f;
    }
  }
  float bfc = b_fc[16 * w + col];
  f32x4 fbias = {bfc, bfc, bfc, bfc};

  // LDS addressing: byte = b*128 + k*2, xor-swizzled by ((b&7)<<4).
  // Read (A-frag): b = col, k = quad*8.. K-half1 is rd_off ^ 64 (bit 6
  // pre-swizzle is 0, so +64 == ^64 on the UNswizzled addr; after the
  // XOR only ^64 is correct).
  const int rd_off = (col * 128 + quad * 16) ^ ((col & 7) << 4);
  const int rd_off1 = rd_off ^ 64;
  int wr_off[4];
#pragma unroll
  for (int r = 0; r < 4; ++r) {
    int b = quad * 4 + r;
    wr_off[r] = (b * 128 + (16 * w + col) * 2) ^ ((b & 7) << 4);
  }

  // h_{-1} = 0 (both buffers)
  *(float4*)(&hmem[0][0] + tid * 16) = make_float4(0.f, 0.f, 0.f, 0.f);

  // xg: per-lane 32B chunk per step; depth-4 prefetch (~1600cyc cover)
  const short* xp = xg + (((size_t)Bk * 4 + w) * 64 + L) * 16;
  uint4 xs[4][2];
#pragma unroll
  for (int s = 0; s < 4; ++s) {
    xs[s][0] = *(const uint4*)(xp + (size_t)s * 65536);
    xs[s][1] = *(const uint4*)(xp + (size_t)s * 65536 + 8);
  }
  const short* xnext = xp + (size_t)4 * 65536;

  float* outp = out + ((size_t)Bk * 16 + quad * 4) * 64 + 16 * w + col;

  float cst[4] = {0.f, 0.f, 0.f, 0.f};

  __syncthreads();  // once; vmcnt drain here is harmless

  // One step. sp = parity: read h_{t-1} from hmem[sp], write h_t to
  // hmem[sp^1]. FC uses the CURRENT step's A-frags (h_{t-1}) -> row t-1.
#define LSTM_STEP(S, PF)                                                   \
  {                                                                        \
    const int sp = (S) & 1;                                                \
    const char* rb = hmem[sp];                                             \
    f16x8 na0 = *(const f16x8_a*)(rb + rd_off);                            \
    f16x8 na1 = *(const f16x8_a*)(rb + rd_off1);                           \
    uint4 xa = xs[(S)][0], xb = xs[(S)][1];                                \
    f32x4 g0 = {bflo(xa.x), bfhi(xa.x), bflo(xa.y), bfhi(xa.y)};           \
    f32x4 g1 = {bflo(xa.z), bfhi(xa.z), bflo(xa.w), bfhi(xa.w)};           \
    f32x4 g2 = {bflo(xb.x), bfhi(xb.x), bflo(xb.y), bfhi(xb.y)};           \
    f32x4 g3 = {bflo(xb.z), bfhi(xb.z), bflo(xb.w), bfhi(xb.w)};           \
    g0 = mfma_f16(na0, whhB[0][0], g0);                                    \
    g1 = mfma_f16(na0, whhB[1][0], g1);                                    \
    g2 = mfma_f16(na0, whhB[2][0], g2);                                    \
    g3 = mfma_f16(na0, whhB[3][0], g3);                                    \
    g0 = mfma_f16(na1, whhB[0][1], g0);                                    \
    g1 = mfma_f16(na1, whhB[1][1], g1);                                    \
    g2 = mfma_f16(na1, whhB[2][1], g2);                                    \
    g3 = mfma_f16(na1, whhB[3][1], g3);                                    \
    if (PF) {                                                              \
      xs[(S)][0] = *(const uint4*)(xnext);                                 \
      xs[(S)][1] = *(const uint4*)(xnext + 8);                             \
      xnext += 65536;                                                      \
    }                                                                      \
    f32x4 fcv = mfma_f16(na0, wfcB[0], fbias);                             \
    fcv = mfma_f16(na1, wfcB[1], fcv);                                     \
    if (t + (S) > 0) {                                                     \
      float* o = outp + (size_t)(t + (S)-1) * 16384;                       \
      o[0] = fcv[0]; o[64] = fcv[1]; o[128] = fcv[2]; o[192] = fcv[3];     \
    }                                                                      \
    char* wb = hmem[sp ^ 1];                                               \
    _Pragma("unroll") for (int r = 0; r < 4; ++r) {                        \
      float iv = fast_sigmoid(g0[r]);                                      \
      float fv = fast_sigmoid(g1[r]);                                      \
      float gv = fast_tanh(g2[r]);                                         \
      float ov = fast_sigmoid(g3[r]);                                      \
      cst[r] = fmaf(fv, cst[r], iv * gv);                                  \
      float hv = ov * fast_tanh(cst[r]);                                   \
      *(_Float16*)(wb + wr_off[r]) = (_Float16)hv;                         \
    }                                                                      \
    __builtin_amdgcn_sched_barrier(0);                                     \
    asm volatile("s_waitcnt lgkmcnt(0)" ::: "memory"); /* DS only: keep */ \
    __builtin_amdgcn_s_barrier();                      /* vmcnt in flight*/ \
    __builtin_amdgcn_sched_barrier(0);                                     \
  }

  for (int t = 0; t < T_STEPS - 4; t += 4) {
    LSTM_STEP(0, 1) LSTM_STEP(1, 1) LSTM_STEP(2, 1) LSTM_STEP(3, 1)
  }
  {  // tail: slots already loaded, no prefetch
    const int t = T_STEPS - 4;
    LSTM_STEP(0, 0) LSTM_STEP(1, 0) LSTM_STEP(2, 0) LSTM_STEP(3, 0)
  }
  {  // final FC on h_{T-1} (in hmem[0] after last step's barrier)
    f16x8 fa0 = *(const f16x8_a*)(hmem[0] + rd_off);
    f16x8 fa1 = *(const f16x8_a*)(hmem[0] + rd_off1);
    f32x4 fcv = mfma_f16(fa0, wfcB[0], fbias);
    fcv = mfma_f16(fa1, wfcB[1], fcv);
    float* o = outp + (size_t)(T_STEPS - 1) * 16384;
    o[0] = fcv[0]; o[64] = fcv[1]; o[128] = fcv[2]; o[192] = fcv[3];
  }
#undef LSTM_STEP
}

extern "C" void kernel_launch(void* const* d_in, const int* in_sizes, int n_in,
                              void* d_out, int out_size, void* d_ws, size_t ws_size,
                              hipStream_t stream) {
  const float* x    = (const float*)d_in[0];
  const float* W_ih = (const float*)d_in[1];
  const float* W_hh = (const float*)d_in[2];
  const float* b_ih = (const float*)d_in[3];
  const float* b_hh = (const float*)d_in[4];
  const float* W_fc = (const float*)d_in[5];
  const float* b_fc = (const float*)d_in[6];
  float* out = (float*)d_out;

  char* ws = (char*)d_ws;
  short* Whi  = (short*)ws;                 // 64 KB
  short* Wlo  = (short*)(ws + 65536);       // 64 KB
  float* bias = (float*)(ws + 131072);      // 1 KB
  short* xg   = (short*)(ws + 132096);      // 268.4 MB bf16, permuted layout

  prep_kernel<<<128, 256, 0, stream>>>(W_ih, b_ih, b_hh, Whi, Wlo, bias);
  phase1_kernel<<<4096, 256, 0, stream>>>(x, Whi, Wlo, bias, xg);
  lstm_fc_kernel<<<16, 256, 0, stream>>>(xg, W_hh, W_fc, b_fc, out);
}

// Round 5
// 1335.751 us; speedup vs baseline: 1.3539x; 1.3539x over previous
//
#include <hip/hip_runtime.h>

// LSTM(T=2048,B=256,IN=128,H=64) + FC(64).
//  prep:    split W_ih into bf16 hi/lo, bias = b_ih + b_hh
//  phase1:  xg = x@W_ih^T + bias (bf16 MFMA, 3-term split), stored PERMUTED
//           for phase2-v2: 8B per (lane,step), fully coalesced stores.
//  lstm_fc v2: 64 blocks x 4 waves; each block owns only 4 batch chains.
//           KEY TRICK: batch b is placed in MFMA A-row 4*b. D rows
//           {0,4,8,12} = (r=0, quad=b) => every lane holds exactly ONE
//           valid (batch,j) pair: batch=quad, j=16w+col. Activation work
//           is 1 set/lane (r=1..3 statically gone) -> 4x less VALU per
//           wave than the 16-chain version, 4x more CUs (64), same MFMA
//           count/wave (8 gate + 2 FC). A-rows with col%4!=0 hold
//           duplicate h data - they only feed D rows we never read, so
//           NO masking needed. h exchanged via 1KB double-buffered LDS
//           (rotated layout: row b rotated by 32B*b -> conflict-free);
//           ONE raw s_barrier+lgkmcnt(0) per step (no vmcnt drain; xg
//           prefetch depth 4 stays in flight).

#define T_STEPS 2048
#define BATCH   256
#define INSZ    128
#define HID     64
#define G4      256   // 4*HID

typedef __attribute__((ext_vector_type(8))) short bf16x8;
typedef __attribute__((ext_vector_type(4))) float f32x4;
typedef __attribute__((ext_vector_type(8))) _Float16 f16x8;
typedef f16x8 __attribute__((may_alias)) f16x8_a;
typedef __attribute__((ext_vector_type(4))) short s16x4;
typedef _Float16 __attribute__((may_alias)) half_a;

__device__ __forceinline__ short f2bf(float f) {
  unsigned u = __float_as_uint(f);
  unsigned r = (u + 0x7fffu + ((u >> 16) & 1u)) >> 16;
  return (short)r;
}
__device__ __forceinline__ float bf2f(short s) {
  return __uint_as_float(((unsigned)(unsigned short)s) << 16);
}
__device__ __forceinline__ float bflo(unsigned u) {
  return __uint_as_float(u << 16);
}
__device__ __forceinline__ float bfhi(unsigned u) {
  return __uint_as_float(u & 0xffff0000u);
}

#define LOG2E 1.44269504088896f
__device__ __forceinline__ float fast_sigmoid(float x) {
  float e = __builtin_amdgcn_exp2f(-LOG2E * x);
  return __builtin_amdgcn_rcpf(1.f + e);
}
__device__ __forceinline__ float fast_tanh(float x) {
  float e = __builtin_amdgcn_exp2f(-2.f * LOG2E * x);
  return fmaf(2.f, __builtin_amdgcn_rcpf(1.f + e), -1.f);
}

__device__ __forceinline__ f32x4 mfma16(bf16x8 a, bf16x8 b, f32x4 c) {
  return __builtin_amdgcn_mfma_f32_16x16x32_bf16(a, b, c, 0, 0, 0);
}
__device__ __forceinline__ f32x4 mfma_f16(f16x8 a, f16x8 b, f32x4 c) {
  return __builtin_amdgcn_mfma_f32_16x16x32_f16(a, b, c, 0, 0, 0);
}

// ---------------- prep: W_ih bf16 hi/lo split + bias sum ----------------
__global__ void prep_kernel(const float* __restrict__ W_ih,
                            const float* __restrict__ b_ih,
                            const float* __restrict__ b_hh,
                            short* __restrict__ Whi, short* __restrict__ Wlo,
                            float* __restrict__ bias) {
  int i = blockIdx.x * 256 + threadIdx.x;  // 128 blocks cover 32768
  float w = W_ih[i];
  short h = f2bf(w);
  Whi[i] = h;
  Wlo[i] = f2bf(w - bf2f(h));
  if (i < G4) bias[i] = b_ih[i] + b_hh[i];
}

// ---------------- phase 1: xg = x @ W_ih^T + bias (MFMA) ----------------
// Output layout (bf16 elems), matching phase2-v2:
//   xg[ (((t*64 + Bk4)*4 + w)*64 + (qd2*16 + col))*4 + tt ]
//     = gate col g = tt*64 + 16*w + col  of batch b = Bk4*4 + qd2
// Per phase1 thread, (rt, r) yields one contiguous 8B chunk (tt=0..3);
// a wave's 16 cols make 128B contiguous segments -> full-line stores.
__global__ __launch_bounds__(256, 2) void phase1_kernel(
    const float* __restrict__ x, const short* __restrict__ Whi,
    const short* __restrict__ Wlo, const float* __restrict__ bias,
    short* __restrict__ xg) {
  int wave = threadIdx.x >> 6, lane = threadIdx.x & 63;
  int col = lane & 15, quad = lane >> 4;
  long rowbase = (long)blockIdx.x * 128 + wave * 32;

  bf16x8 Ah[2][4], Al[2][4];
#pragma unroll
  for (int rt = 0; rt < 2; ++rt) {
    const float* xp = x + (rowbase + rt * 16 + col) * INSZ + quad * 8;
#pragma unroll
    for (int kk = 0; kk < 4; ++kk) {
      float4 v0 = *(const float4*)(xp + kk * 32);
      float4 v1 = *(const float4*)(xp + kk * 32 + 4);
      bf16x8 hh, ll;
      float vv[8] = {v0.x, v0.y, v0.z, v0.w, v1.x, v1.y, v1.z, v1.w};
#pragma unroll
      for (int j = 0; j < 8; ++j) {
        short hb = f2bf(vv[j]);
        hh[j] = hb;
        ll[j] = f2bf(vv[j] - bf2f(hb));
      }
      Ah[rt][kk] = hh;
      Al[rt][kk] = ll;
    }
  }

  const long t = rowbase >> 8;                    // uniform per wave
  const int Bk0 = (int)((rowbase & 255) >> 4);    // even; rt adds +1

#pragma unroll 1
  for (int w4 = 0; w4 < 4; ++w4) {
    float bv[4];
#pragma unroll
    for (int tt = 0; tt < 4; ++tt) bv[tt] = bias[tt * 64 + w4 * 16 + col];
#pragma unroll
    for (int rt = 0; rt < 2; ++rt) {
      f32x4 acc[4];
#pragma unroll
      for (int tt = 0; tt < 4; ++tt) acc[tt] = (f32x4){0.f, 0.f, 0.f, 0.f};
#pragma unroll
      for (int tt = 0; tt < 4; ++tt) {
        const short* bph = Whi + (tt * 64 + w4 * 16 + col) * INSZ + quad * 8;
        const short* bpl = Wlo + (tt * 64 + w4 * 16 + col) * INSZ + quad * 8;
#pragma unroll
        for (int kk = 0; kk < 4; ++kk) {
          bf16x8 bh = *(const bf16x8*)(bph + kk * 32);
          bf16x8 bl = *(const bf16x8*)(bpl + kk * 32);
          acc[tt] = mfma16(Ah[rt][kk], bh, acc[tt]);
          acc[tt] = mfma16(Al[rt][kk], bh, acc[tt]);
          acc[tt] = mfma16(Ah[rt][kk], bl, acc[tt]);
        }
      }
      // store: Bk4 = (Bk0+rt)*4 + quad, lane2 = r*16 + col, 8B per r
      size_t Bk4 = (size_t)(Bk0 + rt) * 4 + quad;
#pragma unroll
      for (int r = 0; r < 4; ++r) {
        s16x4 v;
#pragma unroll
        for (int tt = 0; tt < 4; ++tt) v[tt] = f2bf(acc[tt][r] + bv[tt]);
        size_t off =
            ((((size_t)t * 64 + Bk4) * 4 + (size_t)w4) * 64 + r * 16 + col) * 4;
        *(s16x4*)(xg + off) = v;
      }
    }
  }
}

// ---------------- phase 2: LSTM recurrence + fused FC, v2 ----------------
// 64 blocks x 256 threads. Block = 4 batch chains (b = Bk4*4 + quad).
// Wave w owns gate cols g = tt*64 + 16w + col and FC cols 16w + col.
__global__ __launch_bounds__(256, 1) void lstm_fc_kernel(
    const short* __restrict__ xg, const float* __restrict__ W_hh,
    const float* __restrict__ W_fc, const float* __restrict__ b_fc,
    float* __restrict__ out) {
  const int tid = threadIdx.x;
  const int L = tid & 63, w = tid >> 6;
  const int col = L & 15, quad = L >> 4;
  const int Bk4 = blockIdx.x;

  // f16 h[2 bufs][4 batches][64 j], row b rotated by b*32B (bank-spread)
  __shared__ alignas(16) _Float16 hmem[2][4][64];

  // B-frags: W_hh (4 gate tiles x 2 K-halves) + W_fc (2 K-halves), f16
  f16x8 whhB[4][2];
#pragma unroll
  for (int tt = 0; tt < 4; ++tt) {
    const float* wr = W_hh + (tt * 64 + 16 * w + col) * HID + quad * 8;
#pragma unroll
    for (int kh = 0; kh < 2; ++kh) {
      f16x8 f;
#pragma unroll
      for (int j = 0; j < 8; ++j) f[j] = (_Float16)wr[kh * 32 + j];
      whhB[tt][kh] = f;
    }
  }
  f16x8 wfcB[2];
  {
    const float* fr = W_fc + (16 * w + col) * HID + quad * 8;
#pragma unroll
    for (int kh = 0; kh < 2; ++kh) {
      f16x8 f;
#pragma unroll
      for (int j = 0; j < 8; ++j) f[j] = (_Float16)fr[kh * 32 + j];
      wfcB[kh] = f;
    }
  }
  const float bfc = b_fc[16 * w + col];
  const f32x4 fb = {bfc, 0.f, 0.f, 0.f};

  // LDS addressing (all loop-invariant).
  // write: h(b=quad, j=16w+col) -> row quad, byte ((j*2 + quad*32)&127)
  const int wr_off = quad * 128 + (((16 * w + col) * 2 + quad * 32) & 127);
  // read (A-frag): A row = col holds h[col>>2]; k = quad*8 (+32 for frag1)
  const int br = col >> 2;
  const int rd0 = br * 128 + ((quad * 16 + br * 32) & 127);
  const int rd1 = br * 128 + ((quad * 16 + 64 + br * 32) & 127);

  // zero both h buffers (1KB = 256 floats, one per thread)
  ((float*)hmem)[tid] = 0.f;

  // xg: 8B per lane per step, depth-4 prefetch (~HBM latency x2 cover)
  const short* xp = xg + ((size_t)(Bk4 * 4 + w) * 64 + L) * 4;
  uint2 xs[4];
#pragma unroll
  for (int s = 0; s < 4; ++s) xs[s] = *(const uint2*)(xp + (size_t)s * 65536);
  const short* xnext = xp + (size_t)4 * 65536;

  float* outp = out + (size_t)(Bk4 * 4 + quad) * 64 + 16 * w + col;

  float cc = 0.f;

  __syncthreads();  // once; vmcnt drain here is harmless

  // One step. sp = parity: read h_{t-1} from hmem[sp], write h_t to
  // hmem[sp^1]. FC on CURRENT A-frags (h_{t-1}) -> out row t-1.
#define LSTM_STEP(S, PF)                                                   \
  {                                                                        \
    const int sp = (S) & 1;                                                \
    const char* rb = (const char*)hmem[sp];                                \
    f16x8 na0 = *(const f16x8_a*)(rb + rd0);                               \
    f16x8 na1 = *(const f16x8_a*)(rb + rd1);                               \
    uint2 xa = xs[(S)];                                                    \
    f32x4 c0 = {bflo(xa.x), 0.f, 0.f, 0.f};                                \
    f32x4 c1 = {bfhi(xa.x), 0.f, 0.f, 0.f};                                \
    f32x4 c2 = {bflo(xa.y), 0.f, 0.f, 0.f};                                \
    f32x4 c3 = {bfhi(xa.y), 0.f, 0.f, 0.f};                                \
    c0 = mfma_f16(na0, whhB[0][0], c0);                                    \
    c1 = mfma_f16(na0, whhB[1][0], c1);                                    \
    c2 = mfma_f16(na0, whhB[2][0], c2);                                    \
    c3 = mfma_f16(na0, whhB[3][0], c3);                                    \
    c0 = mfma_f16(na1, whhB[0][1], c0);                                    \
    c1 = mfma_f16(na1, whhB[1][1], c1);                                    \
    c2 = mfma_f16(na1, whhB[2][1], c2);                                    \
    c3 = mfma_f16(na1, whhB[3][1], c3);                                    \
    if (PF) {                                                              \
      xs[(S)] = *(const uint2*)(xnext);                                    \
      xnext += (size_t)65536;                                              \
    }                                                                      \
    f32x4 fcv = mfma_f16(na0, wfcB[0], fb);                                \
    fcv = mfma_f16(na1, wfcB[1], fcv);                                     \
    if (t + (S) > 0) {                                                     \
      outp[(size_t)(t + (S)-1) * 16384] = fcv[0];                          \
    }                                                                      \
    float iv = fast_sigmoid(c0[0]);                                        \
    float fv = fast_sigmoid(c1[0]);                                        \
    float gv = fast_tanh(c2[0]);                                           \
    float ov = fast_sigmoid(c3[0]);                                        \
    cc = fmaf(fv, cc, iv * gv);                                            \
    float hv = ov * fast_tanh(cc);                                         \
    *(half_a*)((char*)hmem[sp ^ 1] + wr_off) = (_Float16)hv;               \
    __builtin_amdgcn_sched_barrier(0);                                     \
    asm volatile("s_waitcnt lgkmcnt(0)" ::: "memory"); /* DS only: keep */ \
    __builtin_amdgcn_s_barrier();                      /* vmcnt in flight*/ \
    __builtin_amdgcn_sched_barrier(0);                                     \
  }

  for (int t = 0; t < T_STEPS - 4; t += 4) {
    LSTM_STEP(0, 1) LSTM_STEP(1, 1) LSTM_STEP(2, 1) LSTM_STEP(3, 1)
  }
  {  // tail: slots already loaded, no prefetch
    const int t = T_STEPS - 4;
    LSTM_STEP(0, 0) LSTM_STEP(1, 0) LSTM_STEP(2, 0) LSTM_STEP(3, 0)
  }
  {  // final FC on h_{T-1} (in hmem[0] after last step's barrier)
    const char* rb = (const char*)hmem[0];
    f16x8 fa0 = *(const f16x8_a*)(rb + rd0);
    f16x8 fa1 = *(const f16x8_a*)(rb + rd1);
    f32x4 fcv = mfma_f16(fa0, wfcB[0], fb);
    fcv = mfma_f16(fa1, wfcB[1], fcv);
    outp[(size_t)(T_STEPS - 1) * 16384] = fcv[0];
  }
#undef LSTM_STEP
}

extern "C" void kernel_launch(void* const* d_in, const int* in_sizes, int n_in,
                              void* d_out, int out_size, void* d_ws, size_t ws_size,
                              hipStream_t stream) {
  const float* x    = (const float*)d_in[0];
  const float* W_ih = (const float*)d_in[1];
  const float* W_hh = (const float*)d_in[2];
  const float* b_ih = (const float*)d_in[3];
  const float* b_hh = (const float*)d_in[4];
  const float* W_fc = (const float*)d_in[5];
  const float* b_fc = (const float*)d_in[6];
  float* out = (float*)d_out;

  char* ws = (char*)d_ws;
  short* Whi  = (short*)ws;                 // 64 KB
  short* Wlo  = (short*)(ws + 65536);       // 64 KB
  float* bias = (float*)(ws + 131072);      // 1 KB
  short* xg   = (short*)(ws + 132096);      // 268.4 MB bf16, permuted v2

  prep_kernel<<<128, 256, 0, stream>>>(W_ih, b_ih, b_hh, Whi, Wlo, bias);
  phase1_kernel<<<4096, 256, 0, stream>>>(x, Whi, Wlo, bias, xg);
  lstm_fc_kernel<<<64, 256, 0, stream>>>(xg, W_hh, W_fc, b_fc, out);
}